// Round 11
// baseline (11.982 us; speedup 1.0000x reference)
//
#include <hip/hip_runtime.h>

// CTC batch cost, faithful port of the JAX reference (incl. the input_len = C
// source bug). B=512, T=512, C=128, L=64 -> S=129 states, TU=128 time steps.
//
// Round 11 structure: chunked producer/consumer pipeline. One block (8 waves)
// per batch. The 64 KB y_pred slab is DMA'd chunk-major (8 chunks x 16 rows):
// wave w's c-th global_load_lds is piece w of chunk c, so per-wave vmcnt
// retires in chunk order. Per chunk: counted s_waitcnt vmcnt(7-c) + raw
// s_barrier => chunk c resident while later chunks stay IN FLIGHT. Wave 0
// computes the 16 recursion steps of chunk c between barriers -- compute is
// fully hidden under the remaining DMA (T3/T4 counted-vmcnt pattern).
//
// Recursion (scaled LINEAR space, no transcendentals on the chain):
//   nb0 = (b0 + b1p) * pbe          b1p = lane-1's b1 via ONE DPP wave_shr:1
//   nb1 = (b0 + fma(skipf,b1p,b1)) * ple
//   nb2 = (b2 + b1) * pbe           (state 128, lane-63 local)
// Blank col per chunk: one ds_read -> lanes 0..15, readlane-immediate
// broadcast per step. Every 8 steps: renorm by wave max (DPP butterfly) with
// an exact power-of-2 scale; exponent accumulates in an int.
// loss = -ln2*(log2(b1+b2)+acc) at lane 63 of wave 0.

#define BB 512
#define TT 512
#define CC 128
#define LL 64
#define TU 128   // input_len = C (source bug, replicated)
#define EPSF 1e-7f
#define LN2F 0.69314718055994530942f
#define NWAVE 8
#define NCHUNK 8
#define CROWS 16  // rows per chunk

template <int CTRL>
__device__ __forceinline__ float dpp_f(float x) {
    const int xi = __float_as_int(x);
    return __int_as_float(__builtin_amdgcn_update_dpp(xi, xi, CTRL, 0xF, 0xF, false));
}

// whole-wave shift-up-by-1 with zero fill into lane 0: one v_mov_dpp.
__device__ __forceinline__ float shift_up1z(float x) {
    const int xi = __float_as_int(x);
    return __int_as_float(__builtin_amdgcn_update_dpp(xi, xi, 0x138 /*wave_shr:1*/,
                                                      0xF, 0xF, true));
}

// wave-wide max via DPP butterfly; global max in lane 63, broadcast via readlane.
__device__ __forceinline__ float wave_max(float v) {
    v = fmaxf(v, dpp_f<0xB1>(v));   // quad_perm [1,0,3,2]
    v = fmaxf(v, dpp_f<0x4E>(v));   // quad_perm [2,3,0,1]
    v = fmaxf(v, dpp_f<0x141>(v));  // row_half_mirror
    v = fmaxf(v, dpp_f<0x140>(v));  // row_mirror
    v = fmaxf(v, dpp_f<0x142>(v));  // row_bcast15
    v = fmaxf(v, dpp_f<0x143>(v));  // row_bcast31
    return __int_as_float(__builtin_amdgcn_readlane(__float_as_int(v), 63));
}

__device__ __forceinline__ void renorm(float& b0, float& b1, float& b2,
                                       int& acc, int lane, int t_done) {
    float m = fmaxf(b0, b1);
    if (lane == 63) m = fmaxf(m, b2);
    m = (lane + 64 >= t_done) ? m : 0.0f;   // only tail-reachable lanes matter
    const float M = wave_max(m);
    int e = 0;
    (void)frexpf(M, &e);                    // native v_frexp_exp; frexpf(0)->e=0
    const float scale = ldexpf(1.0f, -e);   // exact power of two
    b0 *= scale; b1 *= scale; b2 *= scale;
    acc += e;
}

__global__ __launch_bounds__(NWAVE * 64) void ctc_wave(const int* __restrict__ y_true,
                                                       const float* __restrict__ y_pred,
                                                       float* __restrict__ out) {
    __shared__ float lds[TU * CC];          // 64 KB: rows 0..127 of this batch
    const int b = blockIdx.x;
    const int tid = threadIdx.x;
    const int wid = tid >> 6;
    const int lane = tid & 63;
    const float* yp = y_pred + (size_t)b * TT * CC;

    // (1) label load FIRST -- oldest vmem op in every wave, so the counted
    // chunk waits (outstanding <= 7-c) also guarantee it has retired.
    const int lbl = y_true[b * LL + lane];

    // (2) DMA issue, chunk-major: wave w's c-th load = 1 KB piece w of chunk c.
    {
        auto ldsb = (__attribute__((address_space(3))) unsigned int*)lds;
        auto gb   = (const __attribute__((address_space(1))) unsigned int*)yp;
#pragma unroll
        for (int c = 0; c < NCHUNK; ++c) {
            __builtin_amdgcn_global_load_lds(gb + c * 2048 + wid * 256 + lane * 4,
                                             ldsb + c * 2048 + wid * 256, 16, 0, 0);
        }
    }

    // (3) skip flag (compiler waits only on the lbl load: vmcnt(8)).
    const int lblp = __shfl_up(lbl, 1);
    const float skipf = (lane >= 1 && lbl != lblp) ? 1.0f : 0.0f;

    float b0 = 0.0f, b1 = 0.0f, b2 = 0.0f;
    int acc = 0;

#define CHUNK_BODY(c_)                                                          \
    {                                                                           \
        asm volatile("s_waitcnt vmcnt(%0)" :: "i"(NCHUNK - 1 - (c_)) : "memory"); \
        __builtin_amdgcn_s_barrier();                                           \
        if (wid == 0) {                                                         \
            const float pbce =                                                  \
                lds[((c_) * CROWS + (lane & 15)) * CC + (CC - 1)] + EPSF;       \
            float plc[CROWS];                                                   \
            _Pragma("unroll")                                                   \
            for (int j = 0; j < CROWS; ++j)                                     \
                plc[j] = lds[((c_) * CROWS + j) * CC + lbl];                    \
            _Pragma("unroll")                                                   \
            for (int j = 0; j < CROWS; ++j) {                                   \
                const int t = (c_) * CROWS + j;                                 \
                const float pbe = __int_as_float(                               \
                    __builtin_amdgcn_readlane(__float_as_int(pbce), j));        \
                if (t == 0) {                                                   \
                    b0 = (lane == 0) ? pbe : 0.0f;                              \
                    b1 = (lane == 0) ? (plc[0] + EPSF) : 0.0f;                  \
                    b2 = 0.0f;                                                  \
                } else {                                                        \
                    const float ple = plc[j] + EPSF;                            \
                    const float b1p = shift_up1z(b1);                           \
                    const float nb0 = (b0 + b1p) * pbe;                         \
                    const float h   = __builtin_fmaf(skipf, b1p, b1);           \
                    const float nb1 = (b0 + h) * ple;                           \
                    const float nb2 = (b2 + b1) * pbe;                          \
                    b0 = nb0; b1 = nb1; b2 = nb2;                               \
                    if ((t & 7) == 0) renorm(b0, b1, b2, acc, lane, t);         \
                }                                                               \
            }                                                                   \
        }                                                                       \
    }

    CHUNK_BODY(0)
    CHUNK_BODY(1)
    CHUNK_BODY(2)
    CHUNK_BODY(3)
    CHUNK_BODY(4)
    CHUNK_BODY(5)
    CHUNK_BODY(6)
    CHUNK_BODY(7)
#undef CHUNK_BODY

    if (wid == 0 && lane == 63) {
        const float s = b1 + b2;                   // states 127, 128
        out[b] = -LN2F * (__log2f(s) + (float)acc);
    }
}

extern "C" void kernel_launch(void* const* d_in, const int* in_sizes, int n_in,
                              void* d_out, int out_size, void* d_ws, size_t ws_size,
                              hipStream_t stream) {
    const int*   y_true = (const int*)d_in[0];
    const float* y_pred = (const float*)d_in[1];
    float*       out    = (float*)d_out;
    (void)in_sizes; (void)n_in; (void)out_size; (void)d_ws; (void)ws_size;

    ctc_wave<<<BB, NWAVE * 64, 0, stream>>>(y_true, y_pred, out);
}